// Round 5
// baseline (934.619 us; speedup 1.0000x reference)
//
#include <hip/hip_runtime.h>
#include <cstdint>
#include <cmath>

#define NB 4
#define NS 2048
#define ND 2048
#define NH 16
#define NDH 128
#define NM (NB*NS)   // 8192

typedef unsigned short u16;
typedef __bf16 bf16x8 __attribute__((ext_vector_type(8)));
typedef u16    u16x8  __attribute__((ext_vector_type(8)));
typedef u16    u16x4  __attribute__((ext_vector_type(4)));
typedef float  f32x4  __attribute__((ext_vector_type(4)));

__device__ __forceinline__ u16 f2bf(float f) {
  unsigned u = __float_as_uint(f);
  u += 0x7fffu + ((u >> 16) & 1u);   // RNE
  return (u16)(u >> 16);
}
__device__ __forceinline__ float bf2f(u16 h) {
  return __uint_as_float(((unsigned)h) << 16);
}
__device__ __forceinline__ void gld16(const void* g, void* l) {
  __builtin_amdgcn_global_load_lds((__attribute__((address_space(1))) void*)g,
                                   (__attribute__((address_space(3))) void*)l,
                                   16, 0, 0);
}
__device__ __forceinline__ f32x4 mfma_bf16(bf16x8 a, bf16x8 b, f32x4 c) {
  return __builtin_amdgcn_mfma_f32_16x16x32_bf16(a, b, c, 0, 0, 0);
}

// ---------------- fp32 -> bf16 convert (8 elems/thread) ----------------
__global__ void cvt_bf16_kernel(const float* __restrict__ in, u16* __restrict__ out, int n8) {
  int i = blockIdx.x * 256 + threadIdx.x;
  if (i >= n8) return;
  const float4* p = (const float4*)in + (size_t)i * 2;
  float4 a = p[0], b = p[1];
  u16x8 r;
  r[0]=f2bf(a.x); r[1]=f2bf(a.y); r[2]=f2bf(a.z); r[3]=f2bf(a.w);
  r[4]=f2bf(b.x); r[5]=f2bf(b.y); r[6]=f2bf(b.z); r[7]=f2bf(b.w);
  ((u16x8*)out)[i] = r;
}

// ---------------- RoPE tables: cos/sin [S][64] ----------------
__global__ void rope_tables_kernel(float* __restrict__ cosT, float* __restrict__ sinT) {
  int s = blockIdx.x, d = threadIdx.x;
  double inv = pow(10000.0, -(double)d / 64.0);
  float ang = (float)((double)s * inv);
  cosT[s*64 + d] = cosf(ang);
  sinT[s*64 + d] = sinf(ang);
}

// ---------------- RoPE apply, in place on bf16 [NM][ND] ----------------
__global__ void rope_apply_kernel(u16* __restrict__ X, const float* __restrict__ cosT,
                                  const float* __restrict__ sinT) {
  int idx = blockIdx.x * 256 + threadIdx.x;
  int pc = idx & 7, h = (idx >> 3) & (NH - 1), m = idx >> 7;
  int s = m & (NS - 1);
  int d0 = pc * 8;
  size_t base = (size_t)m * ND + h * NDH + d0;
  u16x8 v0 = *(const u16x8*)(X + base);
  u16x8 v1 = *(const u16x8*)(X + base + 64);
  u16x8 r0, r1;
#pragma unroll
  for (int j = 0; j < 8; ++j) {
    float c  = cosT[s*64 + d0 + j];
    float sn = sinT[s*64 + d0 + j];
    float x0 = bf2f(v0[j]), x1 = bf2f(v1[j]);
    r0[j] = f2bf(x0 * c - x1 * sn);
    r1[j] = f2bf(x1 * c + x0 * sn);
  }
  *(u16x8*)(X + base)      = r0;
  *(u16x8*)(X + base + 64) = r1;
}

// ---------------- bf16 GEMM, 256x256 tile, 8-phase pipelined ----------------
#define G_PHASE(BUF, KS, MH, LOADB, STAGE) do {                                   \
  bf16x8 af[4];                                                                   \
  _Pragma("unroll")                                                               \
  for (int mf = 0; mf < 4; ++mf)                                                  \
    af[mf] = *(const bf16x8*)(Asb + (BUF)*32768 + (KS)*16384 + arow + ((MH)*4+mf)*1024); \
  if (LOADB) {                                                                    \
    _Pragma("unroll")                                                             \
    for (int nf = 0; nf < 4; ++nf)                                                \
      bfr[nf] = *(const bf16x8*)(Bsb + (BUF)*32768 + (KS)*16384 + brow + nf*1024); \
  }                                                                               \
  STAGE;                                                                          \
  asm volatile("s_waitcnt vmcnt(8)" ::: "memory");                                \
  __builtin_amdgcn_sched_barrier(0);                                              \
  __builtin_amdgcn_s_barrier();                                                   \
  __builtin_amdgcn_s_setprio(1);                                                  \
  _Pragma("unroll")                                                               \
  for (int mf = 0; mf < 4; ++mf)                                                  \
    _Pragma("unroll")                                                             \
    for (int nf = 0; nf < 4; ++nf)                                                \
      acc[(MH)*4+mf][nf] = mfma_bf16(af[mf], bfr[nf], acc[(MH)*4+mf][nf]);        \
  __builtin_amdgcn_s_setprio(0);                                                  \
  __builtin_amdgcn_s_barrier();                                                   \
} while (0)

template <typename OutT>
__global__ __launch_bounds__(512, 1) void gemm256_kernel(
    const u16* __restrict__ A, const u16* __restrict__ Bw, OutT* __restrict__ C,
    int Nd, int Kd) {
  __shared__ __align__(16) char Asb[65536];
  __shared__ __align__(16) char Bsb[65536];
  int tid = threadIdx.x;
  int wave = tid >> 6, lane = tid & 63;
  int li = lane & 15, lg = lane >> 4;
  int wr = wave >> 2, wc = wave & 3;
  int NTn = Nd >> 8;
  int cpx = (int)gridDim.x >> 3;
  int bid = (int)blockIdx.x;
  int swz = (bid & 7) * cpx + (bid >> 3);
  int m0 = (swz / NTn) << 8, n0 = (swz % NTn) << 8;

  int rswz = (lg * 16) ^ ((li & 3) << 4);
  int arow = (wr * 128 + li) * 64 + rswz;
  int brow = (wc *  64 + li) * 64 + rswz;

  int srow = wave * 16 + (lane >> 2);
  int scswz = ((lane & 3) * 16) ^ ((srow & 3) << 4);
  size_t rowB = (size_t)Kd * 2;
  const char* Asrc = (const char*)A + (size_t)(m0 + srow) * rowB + scswz;
  const char* Bsrc = (const char*)Bw + (size_t)(n0 + srow) * rowB + scswz;
  char* Adst = Asb + wave * 1024;
  char* Bdst = Bsb + wave * 1024;
  size_t half2 = rowB << 7;

  auto stageA = [&](int buf, int ks, int tile) {
    const char* s = Asrc + (size_t)tile * 128 + ks * 64;
    char* d = Adst + buf * 32768 + ks * 16384;
    gld16(s, d);
    gld16(s + half2, d + 8192);
  };
  auto stageB = [&](int buf, int ks, int tile) {
    const char* s = Bsrc + (size_t)tile * 128 + ks * 64;
    char* d = Bdst + buf * 32768 + ks * 16384;
    gld16(s, d);
    gld16(s + half2, d + 8192);
  };

  f32x4 acc[8][4] = {};
  bf16x8 bfr[4];

  int NKT = Kd >> 6;
  int NIT = NKT >> 1;

  stageA(0, 0, 0); stageA(0, 1, 0); stageB(0, 0, 0); stageB(0, 1, 0);
  stageA(1, 0, 1); stageB(1, 0, 1);
  asm volatile("s_waitcnt vmcnt(4)" ::: "memory");
  __builtin_amdgcn_sched_barrier(0);
  __builtin_amdgcn_s_barrier();

  for (int j = 0; j < NIT; ++j) {
    int t1  = 2*j + 1;
    int tn0 = (2*j + 2) & (NKT - 1);
    int tn1 = (2*j + 3) & (NKT - 1);
    G_PHASE(0, 0, 0, true,  { stageA(1, 1, t1);  });
    G_PHASE(0, 0, 1, false, { stageB(1, 1, t1);  });
    G_PHASE(0, 1, 1, true,  { stageA(0, 0, tn0); });
    G_PHASE(0, 1, 0, false, { stageB(0, 0, tn0); });
    G_PHASE(1, 0, 0, true,  { stageA(0, 1, tn0); });
    G_PHASE(1, 0, 1, false, { stageB(0, 1, tn0); });
    G_PHASE(1, 1, 1, true,  { stageA(1, 0, tn1); });
    G_PHASE(1, 1, 0, false, { stageB(1, 0, tn1); });
  }
  asm volatile("s_waitcnt vmcnt(0)" ::: "memory");

  int rbase = m0 + wr*128 + lg*4;
  int cbase = n0 + wc*64 + li;
#pragma unroll
  for (int am = 0; am < 8; ++am)
#pragma unroll
    for (int nf = 0; nf < 4; ++nf)
#pragma unroll
      for (int r = 0; r < 4; ++r) {
        size_t off = (size_t)(rbase + am*16 + r) * Nd + (cbase + nf*16);
        if constexpr (sizeof(OutT) == 2) C[off] = f2bf(acc[am][nf][r]);
        else                             C[off] = acc[am][nf][r];
      }
}

// ---------------- causal flash attention, software-pipelined ----------------
// grid (B*H, S/128), 512 threads = 8 waves; wave wv owns q rows
// [q0 + wv*16, +16), q0 = qt*128, qt = gridDim.y-1-blockIdx.y (heavy first).
// Double-buffered Ks/Vt; counted vmcnt(10) keeps next tile's 10 vmem ops
// (8 V dword loads + 2 K gld16) in flight across both raw barriers.
// Softmax in log2-domain (scale*log2e folded into Q, exp2 direct) + T13
// defer-max (skip O/l rescale when tile max doesn't exceed m_run+8).
__global__ __launch_bounds__(512, 4) void flash_attn_kernel(
    const u16* __restrict__ Q, const u16* __restrict__ K, const u16* __restrict__ V,
    u16* __restrict__ O) {
  __shared__ __align__(16) u16 Ks[2*64*128];  // 32 KB
  __shared__ __align__(16) u16 Vt[2*128*64];  // 32 KB
  __shared__ __align__(16) u16 Pl[8*16*64];   // 16 KB
  int tid = threadIdx.x, wv = tid >> 6, lane = tid & 63;
  int li = lane & 15, lg = lane >> 4;
  int b = blockIdx.x >> 4, h = blockIdx.x & 15;
  int qt = (int)gridDim.y - 1 - (int)blockIdx.y;
  int q0 = qt << 7;
  // 1/sqrt(128) * log2(e): softmax done base-2
  const float qscale = 0.08838834764831845f * 1.4426950408889634f;

  bf16x8 qf[4];
  {
    const u16* qp = Q + (size_t)(b*NS + q0 + wv*16 + li) * ND + h*NDH + lg*8;
#pragma unroll
    for (int kk = 0; kk < 4; ++kk) {
      u16x8 t = *(const u16x8*)(qp + kk*32);
      u16x8 r;
#pragma unroll
      for (int j = 0; j < 8; ++j) r[j] = f2bf(bf2f(t[j]) * qscale);
      qf[kk] = *(bf16x8*)&r;
    }
  }
  f32x4 o[8] = {};
  float m_run[4], l_run[4];
#pragma unroll
  for (int r = 0; r < 4; ++r) { m_run[r] = -INFINITY; l_run[r] = 0.f; }

  const char* Kg = (const char*)(K + (size_t)b*NS*ND + h*NDH);
  const char* Vg = (const char*)(V + (size_t)b*NS*ND + h*NDH);
  const int ROWB = ND * 2;

  int p   = tid & 31;    // dh pair: handles dh {2p,2p+1,2p+64,2p+65}
  int kvg = tid >> 5;    // kv chunk 0..15 (4 kv rows each)

  // per tile: 8 V dword loads -> regs, 2 K gld16 -> Ks[buf]  (10 vmem ops)
  auto issueKV = [&](int kv0, int buf, unsigned (&dlo)[4], unsigned (&dhi)[4]) {
    const char* vrow = Vg + (size_t)(kv0 + kvg*4) * ROWB;
#pragma unroll
    for (int j = 0; j < 4; ++j) {
      dlo[j] = *(const unsigned*)(vrow + j*ROWB + p*4);
      dhi[j] = *(const unsigned*)(vrow + j*ROWB + 128 + p*4);
    }
    char* ksb = (char*)Ks + buf*16384;
#pragma unroll
    for (int c = 0; c < 2; ++c) {
      int s = c*8192 + wv*1024 + lane*16;
      int row = s >> 8;
      int within = (s & 255) ^ ((row & 7) << 4);
      gld16(Kg + (size_t)(kv0 + row)*ROWB + within, ksb + c*8192 + wv*1024);
    }
    __builtin_amdgcn_sched_barrier(0);
  };

  auto dostep = [&](int kv0, int buf, const unsigned (&dlo)[4], const unsigned (&dhi)[4],
                    bool doMask, bool hasNext) {
    if (hasNext) asm volatile("s_waitcnt vmcnt(10)" ::: "memory");
    else         asm volatile("s_waitcnt vmcnt(0)"  ::: "memory");
    __builtin_amdgcn_sched_barrier(0);
    __builtin_amdgcn_s_barrier();        // BAR-A: all waves' K(t) landed
    __builtin_amdgcn_sched_barrier(0);

    char* vtb = (char*)Vt + buf*16384;
    const char* ksb = (const char*)Ks + buf*16384;

    // Vt write: in-register repack (4 kv per thread), swizzled b64 stores
    {
      u16x4 rA, rB, rC, rD;
#pragma unroll
      for (int j = 0; j < 4; ++j) {
        rA[j] = (u16)dlo[j]; rB[j] = (u16)(dlo[j] >> 16);
        rC[j] = (u16)dhi[j]; rD[j] = (u16)(dhi[j] >> 16);
      }
      int a0 = ((2*p   )*128 + kvg*8) ^ (((2*p  ) & 7) << 4);
      int a1 = ((2*p+ 1)*128 + kvg*8) ^ (((2*p+1) & 7) << 4);
      int a2 = ((2*p+64)*128 + kvg*8) ^ (((2*p  ) & 7) << 4);
      int a3 = ((2*p+65)*128 + kvg*8) ^ (((2*p+1) & 7) << 4);
      *(u16x4*)(vtb + a0) = rA;
      *(u16x4*)(vtb + a1) = rB;
      *(u16x4*)(vtb + a2) = rC;
      *(u16x4*)(vtb + a3) = rD;
    }

    // S = Q K^T (16q x 64kv per wave), log2 domain
    f32x4 sc[4] = {};
    __builtin_amdgcn_s_setprio(1);
#pragma unroll
    for (int ni = 0; ni < 4; ++ni) {
      int row = ni*16 + li;
#pragma unroll
      for (int kk = 0; kk < 4; ++kk) {
        int kb = (row*256 + kk*64 + lg*16) ^ ((row & 7) << 4);
        bf16x8 kf = *(const bf16x8*)(ksb + kb);
        sc[ni] = mfma_bf16(qf[kk], kf, sc[ni]);
      }
    }
    __builtin_amdgcn_s_setprio(0);

    // online softmax (base 2)
    int rel = kv0 - q0;                  // kv = rel + ni*16 + li vs q = wv*16+lg*4+r
    float mt[4] = {-INFINITY, -INFINITY, -INFINITY, -INFINITY};
#pragma unroll
    for (int ni = 0; ni < 4; ++ni)
#pragma unroll
      for (int r = 0; r < 4; ++r) {
        float v = sc[ni][r];
        if (doMask && (rel + ni*16 + li > wv*16 + lg*4 + r)) v = -INFINITY;
        sc[ni][r] = v;
        mt[r] = fmaxf(mt[r], v);
      }
#pragma unroll
    for (int d = 1; d < 16; d <<= 1)
#pragma unroll
      for (int r = 0; r < 4; ++r) mt[r] = fmaxf(mt[r], __shfl_xor(mt[r], d, 64));

    // T13 defer-max: rescale only if some row's max grew past m_run + 8
    int ok = 1;
#pragma unroll
    for (int r = 0; r < 4; ++r) ok &= (mt[r] <= m_run[r] + 8.f) ? 1 : 0;
    if (!__all(ok)) {
#pragma unroll
      for (int r = 0; r < 4; ++r) {
        float mn = fmaxf(m_run[r], mt[r]);
        float corr = __builtin_amdgcn_exp2f(m_run[r] - mn);  // -inf -> 0 first tile
        m_run[r] = mn;
        l_run[r] *= corr;
#pragma unroll
        for (int dc = 0; dc < 8; ++dc) o[dc][r] *= corr;
      }
    }

    float rs[4] = {0.f, 0.f, 0.f, 0.f};
#pragma unroll
    for (int ni = 0; ni < 4; ++ni)
#pragma unroll
      for (int r = 0; r < 4; ++r) {
        float pv = __builtin_amdgcn_exp2f(sc[ni][r] - m_run[r]);
        sc[ni][r] = pv;
        rs[r] += pv;
      }
#pragma unroll
    for (int d = 1; d < 16; d <<= 1)
#pragma unroll
      for (int r = 0; r < 4; ++r) rs[r] += __shfl_xor(rs[r], d, 64);
#pragma unroll
    for (int r = 0; r < 4; ++r) l_run[r] += rs[r];

    // P relayout via swizzled per-wave LDS bounce
    bf16x8 pa[2];
    {
      char* Plw = (char*)Pl + wv*2048;
#pragma unroll
      for (int ni = 0; ni < 4; ++ni)
#pragma unroll
        for (int r = 0; r < 4; ++r) {
          int rowp = lg*4 + r;
          int a = (rowp*128 + (ni*16 + li)*2) ^ (((rowp ^ (rowp >> 3)) & 7) << 4);
          *(u16*)(Plw + a) = f2bf(sc[ni][r]);
        }
#pragma unroll
      for (int f = 0; f < 2; ++f) {
        int a = (li*128 + f*64 + lg*16) ^ (((li ^ (li >> 3)) & 7) << 4);
        pa[f] = *(const bf16x8*)(Plw + a);
      }
    }

    asm volatile("s_waitcnt lgkmcnt(0)" ::: "memory");
    __builtin_amdgcn_sched_barrier(0);
    __builtin_amdgcn_s_barrier();        // BAR-B: all waves' Vt[buf] visible
    __builtin_amdgcn_sched_barrier(0);

    // O += P V
    __builtin_amdgcn_s_setprio(1);
#pragma unroll
    for (int dc = 0; dc < 8; ++dc) {
      int dh = dc*16 + li;
#pragma unroll
      for (int f = 0; f < 2; ++f) {
        int a = (dh*128 + (f*32 + lg*8)*2) ^ ((dh & 7) << 4);
        bf16x8 vf = *(const bf16x8*)(vtb + a);
        o[dc] = mfma_bf16(pa[f], vf, o[dc]);
      }
    }
    __builtin_amdgcn_s_setprio(0);
  };

  int nt = (q0 >> 6) + 2;                // kv tiles: 0 .. q0+64
  unsigned dloA[4], dhiA[4], dloB[4], dhiB[4];
  issueKV(0, 0, dloA, dhiA);
  for (int t = 0; ; t += 2) {
    bool h1 = (t+1 < nt);
    if (h1) issueKV((t+1)*64, 1, dloB, dhiB);
    dostep(t*64, 0, dloA, dhiA, t >= nt-2, h1);
    if (!h1) break;
    bool h2 = (t+2 < nt);
    if (h2) issueKV((t+2)*64, 0, dloA, dhiA);
    dostep((t+1)*64, 1, dloB, dhiB, (t+1) >= nt-2, h2);
    if (!h2) break;
  }

  float inv[4];
#pragma unroll
  for (int r = 0; r < 4; ++r) inv[r] = 1.0f / l_run[r];
#pragma unroll
  for (int dc = 0; dc < 8; ++dc)
#pragma unroll
    for (int r = 0; r < 4; ++r) {
      size_t off = (size_t)(b*NS + q0 + wv*16 + lg*4 + r) * ND + h*NDH + dc*16 + li;
      O[off] = f2bf(o[dc][r] * inv[r]);
    }
}

// ---------------- launch ----------------
extern "C" void kernel_launch(void* const* d_in, const int* in_sizes, int n_in,
                              void* d_out, int out_size, void* d_ws, size_t ws_size,
                              hipStream_t stream) {
  const float* x  = (const float*)d_in[0];
  // d_in[1] = attn_mask (causal, handled analytically)
  const float* Wq = (const float*)d_in[2];
  const float* Wk = (const float*)d_in[3];
  const float* Wv = (const float*)d_in[4];
  const float* Wo = (const float*)d_in[5];

  char* ws = (char*)d_ws;
  const size_t SZ_MD = (size_t)NM * ND * 2;
  const size_t SZ_W  = (size_t)ND * ND * 2;
  u16* xb  = (u16*)(ws);
  u16* Qb  = (u16*)(ws + SZ_MD);
  u16* Kb  = (u16*)(ws + 2*SZ_MD);
  u16* Vb  = (u16*)(ws + 3*SZ_MD);
  u16* Ab  = (u16*)(ws + 4*SZ_MD);
  u16* Wqb = (u16*)(ws + 5*SZ_MD);
  u16* Wkb = (u16*)(ws + 5*SZ_MD + SZ_W);
  u16* Wvb = (u16*)(ws + 5*SZ_MD + 2*SZ_W);
  u16* Wob = (u16*)(ws + 5*SZ_MD + 3*SZ_W);
  float* cosT = (float*)(ws + 5*SZ_MD + 4*SZ_W);
  float* sinT = (float*)(ws + 5*SZ_MD + 4*SZ_W + (size_t)NS*64*4);
  size_t needed = 5*SZ_MD + 4*SZ_W + 2*(size_t)NS*64*4;
  if (ws_size < needed) return;

  {
    int n8 = (NM * ND) / 8;
    cvt_bf16_kernel<<<(n8 + 255)/256, 256, 0, stream>>>(x, xb, n8);
    int w8 = (ND * ND) / 8;
    cvt_bf16_kernel<<<(w8 + 255)/256, 256, 0, stream>>>(Wq, Wqb, w8);
    cvt_bf16_kernel<<<(w8 + 255)/256, 256, 0, stream>>>(Wk, Wkb, w8);
    cvt_bf16_kernel<<<(w8 + 255)/256, 256, 0, stream>>>(Wv, Wvb, w8);
    cvt_bf16_kernel<<<(w8 + 255)/256, 256, 0, stream>>>(Wo, Wob, w8);
  }
  rope_tables_kernel<<<NS, 64, 0, stream>>>(cosT, sinT);

  const int GEMM_GRID = (NM/256) * (ND/256);   // 256, %8==0
  gemm256_kernel<u16><<<GEMM_GRID, 512, 0, stream>>>(xb, Wqb, Qb, ND, ND);
  gemm256_kernel<u16><<<GEMM_GRID, 512, 0, stream>>>(xb, Wkb, Kb, ND, ND);
  gemm256_kernel<u16><<<GEMM_GRID, 512, 0, stream>>>(xb, Wvb, Vb, ND, ND);

  {
    int nthr = NM * NH * 8;
    rope_apply_kernel<<<nthr/256, 256, 0, stream>>>(Qb, cosT, sinT);
    rope_apply_kernel<<<nthr/256, 256, 0, stream>>>(Kb, cosT, sinT);
  }

  flash_attn_kernel<<<dim3(NB*NH, NS/128), 512, 0, stream>>>(Qb, Kb, Vb, Ab);

  gemm256_kernel<float><<<GEMM_GRID, 512, 0, stream>>>(Ab, Wob, (float*)d_out, ND, ND);
}

// Round 6
// 530.132 us; speedup vs baseline: 1.7630x; 1.7630x over previous
//
#include <hip/hip_runtime.h>
#include <cstdint>
#include <cmath>

#define NB 4
#define NS 2048
#define ND 2048
#define NH 16
#define NDH 128
#define NM (NB*NS)   // 8192

typedef unsigned short u16;
typedef __bf16 bf16x8 __attribute__((ext_vector_type(8)));
typedef u16    u16x8  __attribute__((ext_vector_type(8)));
typedef u16    u16x4  __attribute__((ext_vector_type(4)));
typedef float  f32x4  __attribute__((ext_vector_type(4)));

__device__ __forceinline__ u16 f2bf(float f) {
  unsigned u = __float_as_uint(f);
  u += 0x7fffu + ((u >> 16) & 1u);   // RNE
  return (u16)(u >> 16);
}
__device__ __forceinline__ float bf2f(u16 h) {
  return __uint_as_float(((unsigned)h) << 16);
}
__device__ __forceinline__ void gld16(const void* g, void* l) {
  __builtin_amdgcn_global_load_lds((__attribute__((address_space(1))) void*)g,
                                   (__attribute__((address_space(3))) void*)l,
                                   16, 0, 0);
}
__device__ __forceinline__ f32x4 mfma_bf16(bf16x8 a, bf16x8 b, f32x4 c) {
  return __builtin_amdgcn_mfma_f32_16x16x32_bf16(a, b, c, 0, 0, 0);
}

// ---------------- fp32 -> bf16 convert (8 elems/thread) ----------------
__global__ void cvt_bf16_kernel(const float* __restrict__ in, u16* __restrict__ out, int n8) {
  int i = blockIdx.x * 256 + threadIdx.x;
  if (i >= n8) return;
  const float4* p = (const float4*)in + (size_t)i * 2;
  float4 a = p[0], b = p[1];
  u16x8 r;
  r[0]=f2bf(a.x); r[1]=f2bf(a.y); r[2]=f2bf(a.z); r[3]=f2bf(a.w);
  r[4]=f2bf(b.x); r[5]=f2bf(b.y); r[6]=f2bf(b.z); r[7]=f2bf(b.w);
  ((u16x8*)out)[i] = r;
}

// ---------------- RoPE tables: cos/sin [S][64] ----------------
__global__ void rope_tables_kernel(float* __restrict__ cosT, float* __restrict__ sinT) {
  int s = blockIdx.x, d = threadIdx.x;
  double inv = pow(10000.0, -(double)d / 64.0);
  float ang = (float)((double)s * inv);
  cosT[s*64 + d] = cosf(ang);
  sinT[s*64 + d] = sinf(ang);
}

// ---------------- RoPE apply, in place on bf16 [NM][ND] ----------------
__global__ void rope_apply_kernel(u16* __restrict__ X, const float* __restrict__ cosT,
                                  const float* __restrict__ sinT) {
  int idx = blockIdx.x * 256 + threadIdx.x;
  int pc = idx & 7, h = (idx >> 3) & (NH - 1), m = idx >> 7;
  int s = m & (NS - 1);
  int d0 = pc * 8;
  size_t base = (size_t)m * ND + h * NDH + d0;
  u16x8 v0 = *(const u16x8*)(X + base);
  u16x8 v1 = *(const u16x8*)(X + base + 64);
  u16x8 r0, r1;
#pragma unroll
  for (int j = 0; j < 8; ++j) {
    float c  = cosT[s*64 + d0 + j];
    float sn = sinT[s*64 + d0 + j];
    float x0 = bf2f(v0[j]), x1 = bf2f(v1[j]);
    r0[j] = f2bf(x0 * c - x1 * sn);
    r1[j] = f2bf(x1 * c + x0 * sn);
  }
  *(u16x8*)(X + base)      = r0;
  *(u16x8*)(X + base + 64) = r1;
}

// ---------------- bf16 GEMM, 256x256 tile, 8-phase pipelined ----------------
#define G_PHASE(BUF, KS, MH, LOADB, STAGE) do {                                   \
  bf16x8 af[4];                                                                   \
  _Pragma("unroll")                                                               \
  for (int mf = 0; mf < 4; ++mf)                                                  \
    af[mf] = *(const bf16x8*)(Asb + (BUF)*32768 + (KS)*16384 + arow + ((MH)*4+mf)*1024); \
  if (LOADB) {                                                                    \
    _Pragma("unroll")                                                             \
    for (int nf = 0; nf < 4; ++nf)                                                \
      bfr[nf] = *(const bf16x8*)(Bsb + (BUF)*32768 + (KS)*16384 + brow + nf*1024); \
  }                                                                               \
  STAGE;                                                                          \
  asm volatile("s_waitcnt vmcnt(8)" ::: "memory");                                \
  __builtin_amdgcn_sched_barrier(0);                                              \
  __builtin_amdgcn_s_barrier();                                                   \
  __builtin_amdgcn_s_setprio(1);                                                  \
  _Pragma("unroll")                                                               \
  for (int mf = 0; mf < 4; ++mf)                                                  \
    _Pragma("unroll")                                                             \
    for (int nf = 0; nf < 4; ++nf)                                                \
      acc[(MH)*4+mf][nf] = mfma_bf16(af[mf], bfr[nf], acc[(MH)*4+mf][nf]);        \
  __builtin_amdgcn_s_setprio(0);                                                  \
  __builtin_amdgcn_s_barrier();                                                   \
} while (0)

template <typename OutT>
__global__ __launch_bounds__(512, 1) void gemm256_kernel(
    const u16* __restrict__ A, const u16* __restrict__ Bw, OutT* __restrict__ C,
    int Nd, int Kd) {
  __shared__ __align__(16) char Asb[65536];
  __shared__ __align__(16) char Bsb[65536];
  int tid = threadIdx.x;
  int wave = tid >> 6, lane = tid & 63;
  int li = lane & 15, lg = lane >> 4;
  int wr = wave >> 2, wc = wave & 3;
  int NTn = Nd >> 8;
  int cpx = (int)gridDim.x >> 3;
  int bid = (int)blockIdx.x;
  int swz = (bid & 7) * cpx + (bid >> 3);
  int m0 = (swz / NTn) << 8, n0 = (swz % NTn) << 8;

  int rswz = (lg * 16) ^ ((li & 3) << 4);
  int arow = (wr * 128 + li) * 64 + rswz;
  int brow = (wc *  64 + li) * 64 + rswz;

  int srow = wave * 16 + (lane >> 2);
  int scswz = ((lane & 3) * 16) ^ ((srow & 3) << 4);
  size_t rowB = (size_t)Kd * 2;
  const char* Asrc = (const char*)A + (size_t)(m0 + srow) * rowB + scswz;
  const char* Bsrc = (const char*)Bw + (size_t)(n0 + srow) * rowB + scswz;
  char* Adst = Asb + wave * 1024;
  char* Bdst = Bsb + wave * 1024;
  size_t half2 = rowB << 7;

  auto stageA = [&](int buf, int ks, int tile) {
    const char* s = Asrc + (size_t)tile * 128 + ks * 64;
    char* d = Adst + buf * 32768 + ks * 16384;
    gld16(s, d);
    gld16(s + half2, d + 8192);
  };
  auto stageB = [&](int buf, int ks, int tile) {
    const char* s = Bsrc + (size_t)tile * 128 + ks * 64;
    char* d = Bdst + buf * 32768 + ks * 16384;
    gld16(s, d);
    gld16(s + half2, d + 8192);
  };

  f32x4 acc[8][4] = {};
  bf16x8 bfr[4];

  int NKT = Kd >> 6;
  int NIT = NKT >> 1;

  stageA(0, 0, 0); stageA(0, 1, 0); stageB(0, 0, 0); stageB(0, 1, 0);
  stageA(1, 0, 1); stageB(1, 0, 1);
  asm volatile("s_waitcnt vmcnt(4)" ::: "memory");
  __builtin_amdgcn_sched_barrier(0);
  __builtin_amdgcn_s_barrier();

  for (int j = 0; j < NIT; ++j) {
    int t1  = 2*j + 1;
    int tn0 = (2*j + 2) & (NKT - 1);
    int tn1 = (2*j + 3) & (NKT - 1);
    G_PHASE(0, 0, 0, true,  { stageA(1, 1, t1);  });
    G_PHASE(0, 0, 1, false, { stageB(1, 1, t1);  });
    G_PHASE(0, 1, 1, true,  { stageA(0, 0, tn0); });
    G_PHASE(0, 1, 0, false, { stageB(0, 0, tn0); });
    G_PHASE(1, 0, 0, true,  { stageA(0, 1, tn0); });
    G_PHASE(1, 0, 1, false, { stageB(0, 1, tn0); });
    G_PHASE(1, 1, 1, true,  { stageA(1, 0, tn1); });
    G_PHASE(1, 1, 0, false, { stageB(1, 0, tn1); });
  }
  asm volatile("s_waitcnt vmcnt(0)" ::: "memory");

  int rbase = m0 + wr*128 + lg*4;
  int cbase = n0 + wc*64 + li;
#pragma unroll
  for (int am = 0; am < 8; ++am)
#pragma unroll
    for (int nf = 0; nf < 4; ++nf)
#pragma unroll
      for (int r = 0; r < 4; ++r) {
        size_t off = (size_t)(rbase + am*16 + r) * Nd + (cbase + nf*16);
        if constexpr (sizeof(OutT) == 2) C[off] = f2bf(acc[am][nf][r]);
        else                             C[off] = acc[am][nf][r];
      }
}

// ---------------- causal flash attention, software-pipelined ----------------
// grid (B*H, S/128), 512 threads = 8 waves; wave wv owns q rows
// [q0 + wv*16, +16), q0 = qt*128, qt = gridDim.y-1-blockIdx.y (heavy first).
// Double-buffered Ks/Vt; counted vmcnt(10) keeps next tile's 10 vmem ops
// (8 V dword loads + 2 K gld16) in flight across both raw barriers.
// Softmax in log2-domain + T13 defer-max.
// launch_bounds (512,2): VGPR cap 256 — (512,4) caused a 64-VGPR cap and
// ~900 MB/dispatch scratch-spill traffic (R5 regression). LDS (80KB) already
// limits to 2 blocks/CU; no reason to cap registers below natural use.
__global__ __launch_bounds__(512, 2) void flash_attn_kernel(
    const u16* __restrict__ Q, const u16* __restrict__ K, const u16* __restrict__ V,
    u16* __restrict__ O) {
  __shared__ __align__(16) u16 Ks[2*64*128];  // 32 KB
  __shared__ __align__(16) u16 Vt[2*128*64];  // 32 KB
  __shared__ __align__(16) u16 Pl[8*16*64];   // 16 KB
  int tid = threadIdx.x, wv = tid >> 6, lane = tid & 63;
  int li = lane & 15, lg = lane >> 4;
  int b = blockIdx.x >> 4, h = blockIdx.x & 15;
  int qt = (int)gridDim.y - 1 - (int)blockIdx.y;
  int q0 = qt << 7;
  // 1/sqrt(128) * log2(e): softmax done base-2
  const float qscale = 0.08838834764831845f * 1.4426950408889634f;

  bf16x8 qf[4];
  {
    const u16* qp = Q + (size_t)(b*NS + q0 + wv*16 + li) * ND + h*NDH + lg*8;
#pragma unroll
    for (int kk = 0; kk < 4; ++kk) {
      u16x8 t = *(const u16x8*)(qp + kk*32);
      u16x8 r;
#pragma unroll
      for (int j = 0; j < 8; ++j) r[j] = f2bf(bf2f(t[j]) * qscale);
      qf[kk] = *(bf16x8*)&r;
    }
  }
  f32x4 o[8] = {};
  float m_run[4], l_run[4];
#pragma unroll
  for (int r = 0; r < 4; ++r) { m_run[r] = -INFINITY; l_run[r] = 0.f; }

  const char* Kg = (const char*)(K + (size_t)b*NS*ND + h*NDH);
  const char* Vg = (const char*)(V + (size_t)b*NS*ND + h*NDH);
  const int ROWB = ND * 2;

  int p   = tid & 31;    // dh pair: handles dh {2p,2p+1,2p+64,2p+65}
  int kvg = tid >> 5;    // kv chunk 0..15 (4 kv rows each)

  // per tile: 8 V dword loads -> regs, 2 K gld16 -> Ks[buf]  (10 vmem ops)
  auto issueKV = [&](int kv0, int buf, unsigned (&dlo)[4], unsigned (&dhi)[4]) {
    const char* vrow = Vg + (size_t)(kv0 + kvg*4) * ROWB;
#pragma unroll
    for (int j = 0; j < 4; ++j) {
      dlo[j] = *(const unsigned*)(vrow + j*ROWB + p*4);
      dhi[j] = *(const unsigned*)(vrow + j*ROWB + 128 + p*4);
    }
    char* ksb = (char*)Ks + buf*16384;
#pragma unroll
    for (int c = 0; c < 2; ++c) {
      int s = c*8192 + wv*1024 + lane*16;
      int row = s >> 8;
      int within = (s & 255) ^ ((row & 7) << 4);
      gld16(Kg + (size_t)(kv0 + row)*ROWB + within, ksb + c*8192 + wv*1024);
    }
    __builtin_amdgcn_sched_barrier(0);
  };

  auto dostep = [&](int kv0, int buf, const unsigned (&dlo)[4], const unsigned (&dhi)[4],
                    bool doMask, bool hasNext) {
    if (hasNext) asm volatile("s_waitcnt vmcnt(10)" ::: "memory");
    else         asm volatile("s_waitcnt vmcnt(0)"  ::: "memory");
    __builtin_amdgcn_sched_barrier(0);
    __builtin_amdgcn_s_barrier();        // BAR-A: all waves' K(t) landed
    __builtin_amdgcn_sched_barrier(0);

    char* vtb = (char*)Vt + buf*16384;
    const char* ksb = (const char*)Ks + buf*16384;

    // Vt write: in-register repack (4 kv per thread), swizzled b64 stores
    {
      u16x4 rA, rB, rC, rD;
#pragma unroll
      for (int j = 0; j < 4; ++j) {
        rA[j] = (u16)dlo[j]; rB[j] = (u16)(dlo[j] >> 16);
        rC[j] = (u16)dhi[j]; rD[j] = (u16)(dhi[j] >> 16);
      }
      int a0 = ((2*p   )*128 + kvg*8) ^ (((2*p  ) & 7) << 4);
      int a1 = ((2*p+ 1)*128 + kvg*8) ^ (((2*p+1) & 7) << 4);
      int a2 = ((2*p+64)*128 + kvg*8) ^ (((2*p  ) & 7) << 4);
      int a3 = ((2*p+65)*128 + kvg*8) ^ (((2*p+1) & 7) << 4);
      *(u16x4*)(vtb + a0) = rA;
      *(u16x4*)(vtb + a1) = rB;
      *(u16x4*)(vtb + a2) = rC;
      *(u16x4*)(vtb + a3) = rD;
    }

    // S = Q K^T (16q x 64kv per wave), log2 domain
    f32x4 sc[4] = {};
    __builtin_amdgcn_s_setprio(1);
#pragma unroll
    for (int ni = 0; ni < 4; ++ni) {
      int row = ni*16 + li;
#pragma unroll
      for (int kk = 0; kk < 4; ++kk) {
        int kb = (row*256 + kk*64 + lg*16) ^ ((row & 7) << 4);
        bf16x8 kf = *(const bf16x8*)(ksb + kb);
        sc[ni] = mfma_bf16(qf[kk], kf, sc[ni]);
      }
    }
    __builtin_amdgcn_s_setprio(0);

    // online softmax (base 2)
    int rel = kv0 - q0;                  // kv = rel + ni*16 + li vs q = wv*16+lg*4+r
    float mt[4] = {-INFINITY, -INFINITY, -INFINITY, -INFINITY};
#pragma unroll
    for (int ni = 0; ni < 4; ++ni)
#pragma unroll
      for (int r = 0; r < 4; ++r) {
        float v = sc[ni][r];
        if (doMask && (rel + ni*16 + li > wv*16 + lg*4 + r)) v = -INFINITY;
        sc[ni][r] = v;
        mt[r] = fmaxf(mt[r], v);
      }
#pragma unroll
    for (int d = 1; d < 16; d <<= 1)
#pragma unroll
      for (int r = 0; r < 4; ++r) mt[r] = fmaxf(mt[r], __shfl_xor(mt[r], d, 64));

    // T13 defer-max: rescale only if some row's max grew past m_run + 8
    int ok = 1;
#pragma unroll
    for (int r = 0; r < 4; ++r) ok &= (mt[r] <= m_run[r] + 8.f) ? 1 : 0;
    if (!__all(ok)) {
#pragma unroll
      for (int r = 0; r < 4; ++r) {
        float mn = fmaxf(m_run[r], mt[r]);
        float corr = __builtin_amdgcn_exp2f(m_run[r] - mn);  // -inf -> 0 first tile
        m_run[r] = mn;
        l_run[r] *= corr;
#pragma unroll
        for (int dc = 0; dc < 8; ++dc) o[dc][r] *= corr;
      }
    }

    float rs[4] = {0.f, 0.f, 0.f, 0.f};
#pragma unroll
    for (int ni = 0; ni < 4; ++ni)
#pragma unroll
      for (int r = 0; r < 4; ++r) {
        float pv = __builtin_amdgcn_exp2f(sc[ni][r] - m_run[r]);
        sc[ni][r] = pv;
        rs[r] += pv;
      }
#pragma unroll
    for (int d = 1; d < 16; d <<= 1)
#pragma unroll
      for (int r = 0; r < 4; ++r) rs[r] += __shfl_xor(rs[r], d, 64);
#pragma unroll
    for (int r = 0; r < 4; ++r) l_run[r] += rs[r];

    // P relayout via swizzled per-wave LDS bounce
    bf16x8 pa[2];
    {
      char* Plw = (char*)Pl + wv*2048;
#pragma unroll
      for (int ni = 0; ni < 4; ++ni)
#pragma unroll
        for (int r = 0; r < 4; ++r) {
          int rowp = lg*4 + r;
          int a = (rowp*128 + (ni*16 + li)*2) ^ (((rowp ^ (rowp >> 3)) & 7) << 4);
          *(u16*)(Plw + a) = f2bf(sc[ni][r]);
        }
#pragma unroll
      for (int f = 0; f < 2; ++f) {
        int a = (li*128 + f*64 + lg*16) ^ (((li ^ (li >> 3)) & 7) << 4);
        pa[f] = *(const bf16x8*)(Plw + a);
      }
    }

    asm volatile("s_waitcnt lgkmcnt(0)" ::: "memory");
    __builtin_amdgcn_sched_barrier(0);
    __builtin_amdgcn_s_barrier();        // BAR-B: all waves' Vt[buf] visible
    __builtin_amdgcn_sched_barrier(0);

    // O += P V
    __builtin_amdgcn_s_setprio(1);
#pragma unroll
    for (int dc = 0; dc < 8; ++dc) {
      int dh = dc*16 + li;
#pragma unroll
      for (int f = 0; f < 2; ++f) {
        int a = (dh*128 + (f*32 + lg*8)*2) ^ ((dh & 7) << 4);
        bf16x8 vf = *(const bf16x8*)(vtb + a);
        o[dc] = mfma_bf16(pa[f], vf, o[dc]);
      }
    }
    __builtin_amdgcn_s_setprio(0);
  };

  int nt = (q0 >> 6) + 2;                // kv tiles: 0 .. q0+64
  unsigned dloA[4], dhiA[4], dloB[4], dhiB[4];
  issueKV(0, 0, dloA, dhiA);
  for (int t = 0; ; t += 2) {
    bool h1 = (t+1 < nt);
    if (h1) issueKV((t+1)*64, 1, dloB, dhiB);
    dostep(t*64, 0, dloA, dhiA, t >= nt-2, h1);
    if (!h1) break;
    bool h2 = (t+2 < nt);
    if (h2) issueKV((t+2)*64, 0, dloA, dhiA);
    dostep((t+1)*64, 1, dloB, dhiB, (t+1) >= nt-2, h2);
    if (!h2) break;
  }

  float inv[4];
#pragma unroll
  for (int r = 0; r < 4; ++r) inv[r] = 1.0f / l_run[r];
#pragma unroll
  for (int dc = 0; dc < 8; ++dc)
#pragma unroll
    for (int r = 0; r < 4; ++r) {
      size_t off = (size_t)(b*NS + q0 + wv*16 + lg*4 + r) * ND + h*NDH + dc*16 + li;
      O[off] = f2bf(o[dc][r] * inv[r]);
    }
}

// ---------------- launch ----------------
extern "C" void kernel_launch(void* const* d_in, const int* in_sizes, int n_in,
                              void* d_out, int out_size, void* d_ws, size_t ws_size,
                              hipStream_t stream) {
  const float* x  = (const float*)d_in[0];
  // d_in[1] = attn_mask (causal, handled analytically)
  const float* Wq = (const float*)d_in[2];
  const float* Wk = (const float*)d_in[3];
  const float* Wv = (const float*)d_in[4];
  const float* Wo = (const float*)d_in[5];

  char* ws = (char*)d_ws;
  const size_t SZ_MD = (size_t)NM * ND * 2;
  const size_t SZ_W  = (size_t)ND * ND * 2;
  u16* xb  = (u16*)(ws);
  u16* Qb  = (u16*)(ws + SZ_MD);
  u16* Kb  = (u16*)(ws + 2*SZ_MD);
  u16* Vb  = (u16*)(ws + 3*SZ_MD);
  u16* Ab  = (u16*)(ws + 4*SZ_MD);
  u16* Wqb = (u16*)(ws + 5*SZ_MD);
  u16* Wkb = (u16*)(ws + 5*SZ_MD + SZ_W);
  u16* Wvb = (u16*)(ws + 5*SZ_MD + 2*SZ_W);
  u16* Wob = (u16*)(ws + 5*SZ_MD + 3*SZ_W);
  float* cosT = (float*)(ws + 5*SZ_MD + 4*SZ_W);
  float* sinT = (float*)(ws + 5*SZ_MD + 4*SZ_W + (size_t)NS*64*4);
  size_t needed = 5*SZ_MD + 4*SZ_W + 2*(size_t)NS*64*4;
  if (ws_size < needed) return;

  {
    int n8 = (NM * ND) / 8;
    cvt_bf16_kernel<<<(n8 + 255)/256, 256, 0, stream>>>(x, xb, n8);
    int w8 = (ND * ND) / 8;
    cvt_bf16_kernel<<<(w8 + 255)/256, 256, 0, stream>>>(Wq, Wqb, w8);
    cvt_bf16_kernel<<<(w8 + 255)/256, 256, 0, stream>>>(Wk, Wkb, w8);
    cvt_bf16_kernel<<<(w8 + 255)/256, 256, 0, stream>>>(Wv, Wvb, w8);
    cvt_bf16_kernel<<<(w8 + 255)/256, 256, 0, stream>>>(Wo, Wob, w8);
  }
  rope_tables_kernel<<<NS, 64, 0, stream>>>(cosT, sinT);

  const int GEMM_GRID = (NM/256) * (ND/256);   // 256, %8==0
  gemm256_kernel<u16><<<GEMM_GRID, 512, 0, stream>>>(xb, Wqb, Qb, ND, ND);
  gemm256_kernel<u16><<<GEMM_GRID, 512, 0, stream>>>(xb, Wkb, Kb, ND, ND);
  gemm256_kernel<u16><<<GEMM_GRID, 512, 0, stream>>>(xb, Wvb, Vb, ND, ND);

  {
    int nthr = NM * NH * 8;
    rope_apply_kernel<<<nthr/256, 256, 0, stream>>>(Qb, cosT, sinT);
    rope_apply_kernel<<<nthr/256, 256, 0, stream>>>(Kb, cosT, sinT);
  }

  flash_attn_kernel<<<dim3(NB*NH, NS/128), 512, 0, stream>>>(Qb, Kb, Vb, Ab);

  gemm256_kernel<float><<<GEMM_GRID, 512, 0, stream>>>(Ab, Wob, (float*)d_out, ND, ND);
}

// Round 7
// 436.714 us; speedup vs baseline: 2.1401x; 1.2139x over previous
//
#include <hip/hip_runtime.h>
#include <cstdint>
#include <cmath>

#define NB 4
#define NS 2048
#define ND 2048
#define NH 16
#define NDH 128
#define NM (NB*NS)   // 8192

typedef unsigned short u16;
typedef __bf16 bf16x8 __attribute__((ext_vector_type(8)));
typedef u16    u16x8  __attribute__((ext_vector_type(8)));
typedef u16    u16x4  __attribute__((ext_vector_type(4)));
typedef float  f32x4  __attribute__((ext_vector_type(4)));
typedef float  f32x16 __attribute__((ext_vector_type(16)));
typedef unsigned u32x4_t __attribute__((ext_vector_type(4)));

__device__ __forceinline__ u16 f2bf(float f) {
  unsigned u = __float_as_uint(f);
  u += 0x7fffu + ((u >> 16) & 1u);   // RNE
  return (u16)(u >> 16);
}
__device__ __forceinline__ float bf2f(u16 h) {
  return __uint_as_float(((unsigned)h) << 16);
}
__device__ __forceinline__ void gld16(const void* g, void* l) {
  __builtin_amdgcn_global_load_lds((__attribute__((address_space(1))) void*)g,
                                   (__attribute__((address_space(3))) void*)l,
                                   16, 0, 0);
}
__device__ __forceinline__ f32x4 mfma_bf16(bf16x8 a, bf16x8 b, f32x4 c) {
  return __builtin_amdgcn_mfma_f32_16x16x32_bf16(a, b, c, 0, 0, 0);
}
__device__ __forceinline__ f32x16 mfma32_bf16(bf16x8 a, bf16x8 b, f32x16 c) {
  return __builtin_amdgcn_mfma_f32_32x32x16_bf16(a, b, c, 0, 0, 0);
}
__device__ __forceinline__ unsigned cvtpk(float lo, float hi) {
  unsigned r;
  asm("v_cvt_pk_bf16_f32 %0, %1, %2" : "=v"(r) : "v"(lo), "v"(hi));
  return r;
}
__device__ __forceinline__ void p32swap(unsigned &a, unsigned &b) {
  asm volatile("v_permlane32_swap_b32 %0, %1" : "+v"(a), "+v"(b));
}

// ---------------- fp32 -> bf16 convert (8 elems/thread) ----------------
__global__ void cvt_bf16_kernel(const float* __restrict__ in, u16* __restrict__ out, int n8) {
  int i = blockIdx.x * 256 + threadIdx.x;
  if (i >= n8) return;
  const float4* p = (const float4*)in + (size_t)i * 2;
  float4 a = p[0], b = p[1];
  u16x8 r;
  r[0]=f2bf(a.x); r[1]=f2bf(a.y); r[2]=f2bf(a.z); r[3]=f2bf(a.w);
  r[4]=f2bf(b.x); r[5]=f2bf(b.y); r[6]=f2bf(b.z); r[7]=f2bf(b.w);
  ((u16x8*)out)[i] = r;
}

// ---------------- RoPE tables: cos/sin [S][64] ----------------
__global__ void rope_tables_kernel(float* __restrict__ cosT, float* __restrict__ sinT) {
  int s = blockIdx.x, d = threadIdx.x;
  double inv = pow(10000.0, -(double)d / 64.0);
  float ang = (float)((double)s * inv);
  cosT[s*64 + d] = cosf(ang);
  sinT[s*64 + d] = sinf(ang);
}

// ---------------- RoPE apply, in place on bf16 [NM][ND] ----------------
__global__ void rope_apply_kernel(u16* __restrict__ X, const float* __restrict__ cosT,
                                  const float* __restrict__ sinT) {
  int idx = blockIdx.x * 256 + threadIdx.x;
  int pc = idx & 7, h = (idx >> 3) & (NH - 1), m = idx >> 7;
  int s = m & (NS - 1);
  int d0 = pc * 8;
  size_t base = (size_t)m * ND + h * NDH + d0;
  u16x8 v0 = *(const u16x8*)(X + base);
  u16x8 v1 = *(const u16x8*)(X + base + 64);
  u16x8 r0, r1;
#pragma unroll
  for (int j = 0; j < 8; ++j) {
    float c  = cosT[s*64 + d0 + j];
    float sn = sinT[s*64 + d0 + j];
    float x0 = bf2f(v0[j]), x1 = bf2f(v1[j]);
    r0[j] = f2bf(x0 * c - x1 * sn);
    r1[j] = f2bf(x1 * c + x0 * sn);
  }
  *(u16x8*)(X + base)      = r0;
  *(u16x8*)(X + base + 64) = r1;
}

// ---------------- bf16 GEMM, 256x256 tile, 8-phase pipelined ----------------
#define G_PHASE(BUF, KS, MH, LOADB, STAGE) do {                                   \
  bf16x8 af[4];                                                                   \
  _Pragma("unroll")                                                               \
  for (int mf = 0; mf < 4; ++mf)                                                  \
    af[mf] = *(const bf16x8*)(Asb + (BUF)*32768 + (KS)*16384 + arow + ((MH)*4+mf)*1024); \
  if (LOADB) {                                                                    \
    _Pragma("unroll")                                                             \
    for (int nf = 0; nf < 4; ++nf)                                                \
      bfr[nf] = *(const bf16x8*)(Bsb + (BUF)*32768 + (KS)*16384 + brow + nf*1024); \
  }                                                                               \
  STAGE;                                                                          \
  asm volatile("s_waitcnt vmcnt(8)" ::: "memory");                                \
  __builtin_amdgcn_sched_barrier(0);                                              \
  __builtin_amdgcn_s_barrier();                                                   \
  __builtin_amdgcn_s_setprio(1);                                                  \
  _Pragma("unroll")                                                               \
  for (int mf = 0; mf < 4; ++mf)                                                  \
    _Pragma("unroll")                                                             \
    for (int nf = 0; nf < 4; ++nf)                                                \
      acc[(MH)*4+mf][nf] = mfma_bf16(af[mf], bfr[nf], acc[(MH)*4+mf][nf]);        \
  __builtin_amdgcn_s_setprio(0);                                                  \
  __builtin_amdgcn_s_barrier();                                                   \
} while (0)

template <typename OutT>
__global__ __launch_bounds__(512, 1) void gemm256_kernel(
    const u16* __restrict__ A, const u16* __restrict__ Bw, OutT* __restrict__ C,
    int Nd, int Kd) {
  __shared__ __align__(16) char Asb[65536];
  __shared__ __align__(16) char Bsb[65536];
  int tid = threadIdx.x;
  int wave = tid >> 6, lane = tid & 63;
  int li = lane & 15, lg = lane >> 4;
  int wr = wave >> 2, wc = wave & 3;
  int NTn = Nd >> 8;
  int cpx = (int)gridDim.x >> 3;
  int bid = (int)blockIdx.x;
  int swz = (bid & 7) * cpx + (bid >> 3);
  int m0 = (swz / NTn) << 8, n0 = (swz % NTn) << 8;

  int rswz = (lg * 16) ^ ((li & 3) << 4);
  int arow = (wr * 128 + li) * 64 + rswz;
  int brow = (wc *  64 + li) * 64 + rswz;

  int srow = wave * 16 + (lane >> 2);
  int scswz = ((lane & 3) * 16) ^ ((srow & 3) << 4);
  size_t rowB = (size_t)Kd * 2;
  const char* Asrc = (const char*)A + (size_t)(m0 + srow) * rowB + scswz;
  const char* Bsrc = (const char*)Bw + (size_t)(n0 + srow) * rowB + scswz;
  char* Adst = Asb + wave * 1024;
  char* Bdst = Bsb + wave * 1024;
  size_t half2 = rowB << 7;

  auto stageA = [&](int buf, int ks, int tile) {
    const char* s = Asrc + (size_t)tile * 128 + ks * 64;
    char* d = Adst + buf * 32768 + ks * 16384;
    gld16(s, d);
    gld16(s + half2, d + 8192);
  };
  auto stageB = [&](int buf, int ks, int tile) {
    const char* s = Bsrc + (size_t)tile * 128 + ks * 64;
    char* d = Bdst + buf * 32768 + ks * 16384;
    gld16(s, d);
    gld16(s + half2, d + 8192);
  };

  f32x4 acc[8][4] = {};
  bf16x8 bfr[4];

  int NKT = Kd >> 6;
  int NIT = NKT >> 1;

  stageA(0, 0, 0); stageA(0, 1, 0); stageB(0, 0, 0); stageB(0, 1, 0);
  stageA(1, 0, 1); stageB(1, 0, 1);
  asm volatile("s_waitcnt vmcnt(4)" ::: "memory");
  __builtin_amdgcn_sched_barrier(0);
  __builtin_amdgcn_s_barrier();

  for (int j = 0; j < NIT; ++j) {
    int t1  = 2*j + 1;
    int tn0 = (2*j + 2) & (NKT - 1);
    int tn1 = (2*j + 3) & (NKT - 1);
    G_PHASE(0, 0, 0, true,  { stageA(1, 1, t1);  });
    G_PHASE(0, 0, 1, false, { stageB(1, 1, t1);  });
    G_PHASE(0, 1, 1, true,  { stageA(0, 0, tn0); });
    G_PHASE(0, 1, 0, false, { stageB(0, 0, tn0); });
    G_PHASE(1, 0, 0, true,  { stageA(0, 1, tn0); });
    G_PHASE(1, 0, 1, false, { stageB(0, 1, tn0); });
    G_PHASE(1, 1, 1, true,  { stageA(1, 0, tn1); });
    G_PHASE(1, 1, 0, false, { stageB(1, 0, tn1); });
  }
  asm volatile("s_waitcnt vmcnt(0)" ::: "memory");

  int rbase = m0 + wr*128 + lg*4;
  int cbase = n0 + wc*64 + li;
#pragma unroll
  for (int am = 0; am < 8; ++am)
#pragma unroll
    for (int nf = 0; nf < 4; ++nf)
#pragma unroll
      for (int r = 0; r < 4; ++r) {
        size_t off = (size_t)(rbase + am*16 + r) * Nd + (cbase + nf*16);
        if constexpr (sizeof(OutT) == 2) C[off] = f2bf(acc[am][nf][r]);
        else                             C[off] = acc[am][nf][r];
      }
}

// ---------------- causal flash attention, 32x32 swapped-QK^T ----------------
// grid (B*H, NS/256), 512 threads = 8 waves; wave wv owns q rows
// [q0 + wv*32, +32), q0 = qt*256 (heavy tiles dispatch first).
// Swapped QK^T: p = mfma32(K_frag, Q_frag) -> lane holds P row for q=lane&31
// (32 kv in p0/p1 regs, split with lane^32). Softmax fully in-register;
// P->bf16 A-frag via 16 cvt_pk + 8 permlane32_swap (T12), no LDS P bounce.
// Double-buffered Ks/Vt (64 KB), counted vmcnt(10) pipeline as before.
__global__ __launch_bounds__(512, 2) void flash_attn_kernel(
    const u16* __restrict__ Q, const u16* __restrict__ K, const u16* __restrict__ V,
    u16* __restrict__ O) {
  __shared__ __align__(16) u16 Ks[2*64*128];  // 32 KB swizzled [kv][dh]
  __shared__ __align__(16) u16 Vt[2*128*64];  // 32 KB swizzled [dh][kv]
  int tid = threadIdx.x, wv = tid >> 6, lane = tid & 63;
  int ql = lane & 31, hi = lane >> 5;
  int b = blockIdx.x >> 4, h = blockIdx.x & 15;
  int qt = (int)gridDim.y - 1 - (int)blockIdx.y;
  int q0 = qt << 8;
  int qw = q0 + wv*32;          // wave q base
  int qa = qw + ql;             // this lane's q row
  int swzl = (ql & 7) << 4;     // LDS XOR swizzle for this lane's rows
  const float qscale = 0.08838834764831845f * 1.4426950408889634f; // /sqrt(128)*log2e

  // Q fragments: B-frag layout (col q = lane&31, k = hi*8+j), 8 d-slices of 16
  bf16x8 qf[8];
  {
    const u16* qp = Q + (size_t)(b*NS + qa) * ND + h*NDH + hi*8;
#pragma unroll
    for (int ds = 0; ds < 8; ++ds) {
      u16x8 t = *(const u16x8*)(qp + ds*16);
      u16x8 r;
#pragma unroll
      for (int j = 0; j < 8; ++j) r[j] = f2bf(bf2f(t[j]) * qscale);
      qf[ds] = *(bf16x8*)&r;
    }
  }
  f32x16 o0 = {}, o1 = {}, o2 = {}, o3 = {};   // O dh-subtiles 0..3
  float m_run = -INFINITY, l_run = 0.f;

  const char* Kg = (const char*)(K + (size_t)b*NS*ND + h*NDH);
  const char* Vg = (const char*)(V + (size_t)b*NS*ND + h*NDH);
  const int ROWB = ND * 2;

  int p   = tid & 31;    // dh pair for V repack
  int kvg = tid >> 5;    // kv chunk 0..15 (4 kv rows each)

  auto issueKV = [&](int kv0, int buf, unsigned (&dlo)[4], unsigned (&dhi)[4]) {
    const char* vrow = Vg + (size_t)(kv0 + kvg*4) * ROWB;
#pragma unroll
    for (int j = 0; j < 4; ++j) {
      dlo[j] = *(const unsigned*)(vrow + j*ROWB + p*4);
      dhi[j] = *(const unsigned*)(vrow + j*ROWB + 128 + p*4);
    }
    char* ksb = (char*)Ks + buf*16384;
#pragma unroll
    for (int c = 0; c < 2; ++c) {
      int s = c*8192 + wv*1024 + lane*16;
      int row = s >> 8;
      int within = (s & 255) ^ ((row & 7) << 4);
      gld16(Kg + (size_t)(kv0 + row)*ROWB + within, ksb + c*8192 + wv*1024);
    }
    __builtin_amdgcn_sched_barrier(0);
  };

  auto dostep = [&](int kv0, int buf, const unsigned (&dlo)[4], const unsigned (&dhi)[4],
                    bool hasNext) {
    if (hasNext) asm volatile("s_waitcnt vmcnt(10)" ::: "memory");
    else         asm volatile("s_waitcnt vmcnt(0)"  ::: "memory");
    __builtin_amdgcn_sched_barrier(0);
    __builtin_amdgcn_s_barrier();        // BAR-A: all waves' K(t) landed
    __builtin_amdgcn_sched_barrier(0);

    char* vtb = (char*)Vt + buf*16384;
    const char* ksb = (const char*)Ks + buf*16384;

    // Vt write: in-register repack (4 kv per thread), swizzled b64 stores
    {
      u16x4 rA, rB, rC, rD;
#pragma unroll
      for (int j = 0; j < 4; ++j) {
        rA[j] = (u16)dlo[j]; rB[j] = (u16)(dlo[j] >> 16);
        rC[j] = (u16)dhi[j]; rD[j] = (u16)(dhi[j] >> 16);
      }
      int a0 = ((2*p   )*128 + kvg*8) ^ (((2*p  ) & 7) << 4);
      int a1 = ((2*p+ 1)*128 + kvg*8) ^ (((2*p+1) & 7) << 4);
      int a2 = ((2*p+64)*128 + kvg*8) ^ (((2*p  ) & 7) << 4);
      int a3 = ((2*p+65)*128 + kvg*8) ^ (((2*p+1) & 7) << 4);
      *(u16x4*)(vtb + a0) = rA;
      *(u16x4*)(vtb + a1) = rB;
      *(u16x4*)(vtb + a2) = rC;
      *(u16x4*)(vtb + a3) = rD;
    }

    // S = K Q^T (swapped): p0 = kv 0..31, p1 = kv 32..63; lane's q = ql
    f32x16 p0 = {}, p1 = {};
    __builtin_amdgcn_s_setprio(1);
#pragma unroll
    for (int ds = 0; ds < 8; ++ds) {
      bf16x8 kf0 = *(const bf16x8*)(ksb + ((ql*256 + ds*32 + hi*16) ^ swzl));
      p0 = mfma32_bf16(kf0, qf[ds], p0);
      bf16x8 kf1 = *(const bf16x8*)(ksb + (((32+ql)*256 + ds*32 + hi*16) ^ swzl) + 0);
      p1 = mfma32_bf16(kf1, qf[ds], p1);
    }
    __builtin_amdgcn_s_setprio(0);

    // causal mask: kv_abs = kv0 + s*32 + (r&3)+8*(r>>2)+4*hi  vs  qa
    if (kv0 + 63 > qw) {
      int thresh = qa - kv0 - 4*hi;
#pragma unroll
      for (int r = 0; r < 16; ++r) {
        int c0 = (r & 3) + 8*(r >> 2);
        p0[r] = (c0      > thresh) ? -INFINITY : p0[r];
        p1[r] = (c0 + 32 > thresh) ? -INFINITY : p1[r];
      }
    }

    // row max (in-reg tree + one cross-pair shuffle)
    float mx[16];
#pragma unroll
    for (int r = 0; r < 16; ++r) mx[r] = fmaxf(p0[r], p1[r]);
#pragma unroll
    for (int s = 8; s > 0; s >>= 1)
#pragma unroll
      for (int r = 0; r < 8; ++r) if (r < s) mx[r] = fmaxf(mx[r], mx[r + s]);
    float pmax = fmaxf(mx[0], __shfl_xor(mx[0], 32, 64));

    // T13 defer-max
    if (!__all(pmax <= m_run + 8.f)) {
      float mn = fmaxf(m_run, pmax);
      float corr = __builtin_amdgcn_exp2f(m_run - mn);
      m_run = mn; l_run *= corr;
#pragma unroll
      for (int r = 0; r < 16; ++r) {
        float cw = __shfl(corr, (r & 3) + 8*(r >> 2) + 4*hi, 64);
        o0[r] *= cw; o1[r] *= cw; o2[r] *= cw; o3[r] *= cw;
      }
    }

    // exp2 + row sum
    float sm[16];
#pragma unroll
    for (int r = 0; r < 16; ++r) {
      p0[r] = __builtin_amdgcn_exp2f(p0[r] - m_run);
      p1[r] = __builtin_amdgcn_exp2f(p1[r] - m_run);
      sm[r] = p0[r] + p1[r];
    }
#pragma unroll
    for (int s = 8; s > 0; s >>= 1)
#pragma unroll
      for (int r = 0; r < 8; ++r) if (r < s) sm[r] += sm[r + s];
    l_run += sm[0] + __shfl_xor(sm[0], 32, 64);

    // P -> bf16 A-frags: 16 cvt_pk + 8 permlane32_swap (T12)
    bf16x8 pa0, pa1, pa2, pa3;
#define MKPA(P, B, OUT) {                              \
      unsigned a0 = cvtpk(P[(B)+0], P[(B)+1]);         \
      unsigned b0 = cvtpk(P[(B)+4], P[(B)+5]);         \
      p32swap(a0, b0);                                 \
      unsigned a1 = cvtpk(P[(B)+2], P[(B)+3]);         \
      unsigned b1 = cvtpk(P[(B)+6], P[(B)+7]);         \
      p32swap(a1, b1);                                 \
      u32x4_t w; w[0]=a0; w[1]=a1; w[2]=b0; w[3]=b1;   \
      OUT = *(bf16x8*)&w; }
    MKPA(p0, 0, pa0)
    MKPA(p0, 8, pa1)
    MKPA(p1, 0, pa2)
    MKPA(p1, 8, pa3)
#undef MKPA

    asm volatile("s_waitcnt lgkmcnt(0)" ::: "memory");  // my Vt writes done
    __builtin_amdgcn_sched_barrier(0);
    __builtin_amdgcn_s_barrier();        // BAR-B: all waves' Vt[buf] visible
    __builtin_amdgcn_sched_barrier(0);

    // O += P V  (A = P frag, B = V^T column frag)
    __builtin_amdgcn_s_setprio(1);
#define PVT(OT, T) {                                                        \
      _Pragma("unroll")                                                     \
      for (int ks = 0; ks < 4; ++ks) {                                      \
        int a = ((((T)*32 + ql)*128 + ks*32 + hi*16) ^ swzl);               \
        bf16x8 vf = *(const bf16x8*)(vtb + a);                              \
        OT = mfma32_bf16(ks==0?pa0:ks==1?pa1:ks==2?pa2:pa3, vf, OT);        \
      } }
    PVT(o0, 0)
    PVT(o1, 1)
    PVT(o2, 2)
    PVT(o3, 3)
#undef PVT
    __builtin_amdgcn_s_setprio(0);
  };

  int nt = 4*qt + 4;                     // kv tiles 0 .. q0+255
  unsigned dloA[4], dhiA[4], dloB[4], dhiB[4];
  issueKV(0, 0, dloA, dhiA);
  for (int t = 0; ; t += 2) {
    bool h1 = (t+1 < nt);
    if (h1) issueKV((t+1)*64, 1, dloB, dhiB);
    dostep(t*64, 0, dloA, dhiA, h1);
    if (!h1) break;
    bool h2 = (t+2 < nt);
    if (h2) issueKV((t+2)*64, 0, dloA, dhiA);
    dostep((t+1)*64, 1, dloB, dhiB, h2);
    if (!h2) break;
  }

  // epilogue: O rows q' = (r&3)+8*(r>>2)+4*hi, cols dh = t*32+ql
  float inv = 1.0f / l_run;
#pragma unroll
  for (int r = 0; r < 16; ++r) {
    int crow = (r & 3) + 8*(r >> 2) + 4*hi;
    float iv = __shfl(inv, crow, 64);
    size_t base = (size_t)(b*NS + qw + crow) * ND + h*NDH + ql;
    O[base +  0] = f2bf(o0[r] * iv);
    O[base + 32] = f2bf(o1[r] * iv);
    O[base + 64] = f2bf(o2[r] * iv);
    O[base + 96] = f2bf(o3[r] * iv);
  }
}

// ---------------- launch ----------------
extern "C" void kernel_launch(void* const* d_in, const int* in_sizes, int n_in,
                              void* d_out, int out_size, void* d_ws, size_t ws_size,
                              hipStream_t stream) {
  const float* x  = (const float*)d_in[0];
  // d_in[1] = attn_mask (causal, handled analytically)
  const float* Wq = (const float*)d_in[2];
  const float* Wk = (const float*)d_in[3];
  const float* Wv = (const float*)d_in[4];
  const float* Wo = (const float*)d_in[5];

  char* ws = (char*)d_ws;
  const size_t SZ_MD = (size_t)NM * ND * 2;
  const size_t SZ_W  = (size_t)ND * ND * 2;
  u16* xb  = (u16*)(ws);
  u16* Qb  = (u16*)(ws + SZ_MD);
  u16* Kb  = (u16*)(ws + 2*SZ_MD);
  u16* Vb  = (u16*)(ws + 3*SZ_MD);
  u16* Ab  = (u16*)(ws + 4*SZ_MD);
  u16* Wqb = (u16*)(ws + 5*SZ_MD);
  u16* Wkb = (u16*)(ws + 5*SZ_MD + SZ_W);
  u16* Wvb = (u16*)(ws + 5*SZ_MD + 2*SZ_W);
  u16* Wob = (u16*)(ws + 5*SZ_MD + 3*SZ_W);
  float* cosT = (float*)(ws + 5*SZ_MD + 4*SZ_W);
  float* sinT = (float*)(ws + 5*SZ_MD + 4*SZ_W + (size_t)NS*64*4);
  size_t needed = 5*SZ_MD + 4*SZ_W + 2*(size_t)NS*64*4;
  if (ws_size < needed) return;

  {
    int n8 = (NM * ND) / 8;
    cvt_bf16_kernel<<<(n8 + 255)/256, 256, 0, stream>>>(x, xb, n8);
    int w8 = (ND * ND) / 8;
    cvt_bf16_kernel<<<(w8 + 255)/256, 256, 0, stream>>>(Wq, Wqb, w8);
    cvt_bf16_kernel<<<(w8 + 255)/256, 256, 0, stream>>>(Wk, Wkb, w8);
    cvt_bf16_kernel<<<(w8 + 255)/256, 256, 0, stream>>>(Wv, Wvb, w8);
    cvt_bf16_kernel<<<(w8 + 255)/256, 256, 0, stream>>>(Wo, Wob, w8);
  }
  rope_tables_kernel<<<NS, 64, 0, stream>>>(cosT, sinT);

  const int GEMM_GRID = (NM/256) * (ND/256);   // 256, %8==0
  gemm256_kernel<u16><<<GEMM_GRID, 512, 0, stream>>>(xb, Wqb, Qb, ND, ND);
  gemm256_kernel<u16><<<GEMM_GRID, 512, 0, stream>>>(xb, Wkb, Kb, ND, ND);
  gemm256_kernel<u16><<<GEMM_GRID, 512, 0, stream>>>(xb, Wvb, Vb, ND, ND);

  {
    int nthr = NM * NH * 8;
    rope_apply_kernel<<<nthr/256, 256, 0, stream>>>(Qb, cosT, sinT);
    rope_apply_kernel<<<nthr/256, 256, 0, stream>>>(Kb, cosT, sinT);
  }

  flash_attn_kernel<<<dim3(NB*NH, NS/256), 512, 0, stream>>>(Qb, Kb, Vb, Ab);

  gemm256_kernel<float><<<GEMM_GRID, 512, 0, stream>>>(Ab, Wob, (float*)d_out, ND, ND);
}

// Round 8
// 433.352 us; speedup vs baseline: 2.1567x; 1.0078x over previous
//
#include <hip/hip_runtime.h>
#include <cstdint>
#include <cmath>

#define NB 4
#define NS 2048
#define ND 2048
#define NH 16
#define NDH 128
#define NM (NB*NS)   // 8192

typedef unsigned short u16;
typedef __bf16 bf16x8 __attribute__((ext_vector_type(8)));
typedef u16    u16x8  __attribute__((ext_vector_type(8)));
typedef u16    u16x4  __attribute__((ext_vector_type(4)));
typedef float  f32x4  __attribute__((ext_vector_type(4)));
typedef float  f32x16 __attribute__((ext_vector_type(16)));
typedef unsigned u32x4_t __attribute__((ext_vector_type(4)));

__device__ __forceinline__ u16 f2bf(float f) {
  unsigned u = __float_as_uint(f);
  u += 0x7fffu + ((u >> 16) & 1u);   // RNE
  return (u16)(u >> 16);
}
__device__ __forceinline__ float bf2f(u16 h) {
  return __uint_as_float(((unsigned)h) << 16);
}
__device__ __forceinline__ void gld16(const void* g, void* l) {
  __builtin_amdgcn_global_load_lds((__attribute__((address_space(1))) void*)g,
                                   (__attribute__((address_space(3))) void*)l,
                                   16, 0, 0);
}
__device__ __forceinline__ f32x4 mfma_bf16(bf16x8 a, bf16x8 b, f32x4 c) {
  return __builtin_amdgcn_mfma_f32_16x16x32_bf16(a, b, c, 0, 0, 0);
}
__device__ __forceinline__ f32x16 mfma32_bf16(bf16x8 a, bf16x8 b, f32x16 c) {
  return __builtin_amdgcn_mfma_f32_32x32x16_bf16(a, b, c, 0, 0, 0);
}
__device__ __forceinline__ unsigned cvtpk(float lo, float hi) {
  unsigned r;
  asm("v_cvt_pk_bf16_f32 %0, %1, %2" : "=v"(r) : "v"(lo), "v"(hi));
  return r;
}
__device__ __forceinline__ void p32swap(unsigned &a, unsigned &b) {
  asm volatile("v_permlane32_swap_b32 %0, %1" : "+v"(a), "+v"(b));
}

// ---------------- fp32 -> bf16 convert (8 elems/thread) ----------------
__global__ void cvt_bf16_kernel(const float* __restrict__ in, u16* __restrict__ out, int n8) {
  int i = blockIdx.x * 256 + threadIdx.x;
  if (i >= n8) return;
  const float4* p = (const float4*)in + (size_t)i * 2;
  float4 a = p[0], b = p[1];
  u16x8 r;
  r[0]=f2bf(a.x); r[1]=f2bf(a.y); r[2]=f2bf(a.z); r[3]=f2bf(a.w);
  r[4]=f2bf(b.x); r[5]=f2bf(b.y); r[6]=f2bf(b.z); r[7]=f2bf(b.w);
  ((u16x8*)out)[i] = r;
}

// ---------------- RoPE tables: cos/sin [S][64] ----------------
__global__ void rope_tables_kernel(float* __restrict__ cosT, float* __restrict__ sinT) {
  int s = blockIdx.x, d = threadIdx.x;
  double inv = pow(10000.0, -(double)d / 64.0);
  float ang = (float)((double)s * inv);
  cosT[s*64 + d] = cosf(ang);
  sinT[s*64 + d] = sinf(ang);
}

// ---------------- RoPE apply, in place on bf16 [NM][ND] ----------------
__global__ void rope_apply_kernel(u16* __restrict__ X, const float* __restrict__ cosT,
                                  const float* __restrict__ sinT) {
  int idx = blockIdx.x * 256 + threadIdx.x;
  int pc = idx & 7, h = (idx >> 3) & (NH - 1), m = idx >> 7;
  int s = m & (NS - 1);
  int d0 = pc * 8;
  size_t base = (size_t)m * ND + h * NDH + d0;
  u16x8 v0 = *(const u16x8*)(X + base);
  u16x8 v1 = *(const u16x8*)(X + base + 64);
  u16x8 r0, r1;
#pragma unroll
  for (int j = 0; j < 8; ++j) {
    float c  = cosT[s*64 + d0 + j];
    float sn = sinT[s*64 + d0 + j];
    float x0 = bf2f(v0[j]), x1 = bf2f(v1[j]);
    r0[j] = f2bf(x0 * c - x1 * sn);
    r1[j] = f2bf(x1 * c + x0 * sn);
  }
  *(u16x8*)(X + base)      = r0;
  *(u16x8*)(X + base + 64) = r1;
}

// ---------------- bf16 GEMM, 256x256 tile, 8-phase pipelined ----------------
// R8 schedule (T3/T4): single barrier per phase, counted vmcnt(4) ONLY at
// phases 4 and 8 (once per K-tile).  In-flight ledger (2 gld16/phase):
// at each wait, outstanding = 12; vmcnt(4) forces exactly the 8 loads whose
// slabs are read during the following 4 phases.  WAR: each stage-target
// slab's last reader finished before the preceding barrier (checked per
// phase); intra-phase write/read slabs disjoint.  sched_barrier(0) after
// s_barrier pins next-phase ds_reads (s_barrier is not an IR memory fence).
#define G_PHASE(BUF, KS, MH, LOADB, WAITV, STAGE) do {                            \
  bf16x8 af[4];                                                                   \
  _Pragma("unroll")                                                               \
  for (int mf = 0; mf < 4; ++mf)                                                  \
    af[mf] = *(const bf16x8*)(Asb + (BUF)*32768 + (KS)*16384 + arow + ((MH)*4+mf)*1024); \
  if (LOADB) {                                                                    \
    _Pragma("unroll")                                                             \
    for (int nf = 0; nf < 4; ++nf)                                                \
      bfr[nf] = *(const bf16x8*)(Bsb + (BUF)*32768 + (KS)*16384 + brow + nf*1024); \
  }                                                                               \
  STAGE;                                                                          \
  __builtin_amdgcn_s_setprio(1);                                                  \
  _Pragma("unroll")                                                               \
  for (int mf = 0; mf < 4; ++mf)                                                  \
    _Pragma("unroll")                                                             \
    for (int nf = 0; nf < 4; ++nf)                                                \
      acc[(MH)*4+mf][nf] = mfma_bf16(af[mf], bfr[nf], acc[(MH)*4+mf][nf]);        \
  __builtin_amdgcn_s_setprio(0);                                                  \
  if (WAITV) {                                                                    \
    asm volatile("s_waitcnt vmcnt(4)" ::: "memory");                              \
    __builtin_amdgcn_sched_barrier(0);                                            \
  }                                                                               \
  __builtin_amdgcn_s_barrier();                                                   \
  __builtin_amdgcn_sched_barrier(0);                                              \
} while (0)

template <typename OutT>
__global__ __launch_bounds__(512, 1) void gemm256_kernel(
    const u16* __restrict__ A, const u16* __restrict__ Bw, OutT* __restrict__ C,
    int Nd, int Kd) {
  __shared__ __align__(16) char Asb[65536];
  __shared__ __align__(16) char Bsb[65536];
  int tid = threadIdx.x;
  int wave = tid >> 6, lane = tid & 63;
  int li = lane & 15, lg = lane >> 4;
  int wr = wave >> 2, wc = wave & 3;
  int NTn = Nd >> 8;
  int cpx = (int)gridDim.x >> 3;
  int bid = (int)blockIdx.x;
  int swz = (bid & 7) * cpx + (bid >> 3);
  int m0 = (swz / NTn) << 8, n0 = (swz % NTn) << 8;

  int rswz = (lg * 16) ^ ((li & 3) << 4);
  int arow = (wr * 128 + li) * 64 + rswz;
  int brow = (wc *  64 + li) * 64 + rswz;

  int srow = wave * 16 + (lane >> 2);
  int scswz = ((lane & 3) * 16) ^ ((srow & 3) << 4);
  size_t rowB = (size_t)Kd * 2;
  const char* Asrc = (const char*)A + (size_t)(m0 + srow) * rowB + scswz;
  const char* Bsrc = (const char*)Bw + (size_t)(n0 + srow) * rowB + scswz;
  char* Adst = Asb + wave * 1024;
  char* Bdst = Bsb + wave * 1024;
  size_t half2 = rowB << 7;

  auto stageA = [&](int buf, int ks, int tile) {
    const char* s = Asrc + (size_t)tile * 128 + ks * 64;
    char* d = Adst + buf * 32768 + ks * 16384;
    gld16(s, d);
    gld16(s + half2, d + 8192);
  };
  auto stageB = [&](int buf, int ks, int tile) {
    const char* s = Bsrc + (size_t)tile * 128 + ks * 64;
    char* d = Bdst + buf * 32768 + ks * 16384;
    gld16(s, d);
    gld16(s + half2, d + 8192);
  };

  f32x4 acc[8][4] = {};
  bf16x8 bfr[4];

  int NKT = Kd >> 6;
  int NIT = NKT >> 1;

  // prologue: tile0 fully + tile1 ks0 (12 loads); vmcnt(4) -> tile0 landed
  stageA(0, 0, 0); stageA(0, 1, 0); stageB(0, 0, 0); stageB(0, 1, 0);
  stageA(1, 0, 1); stageB(1, 0, 1);
  asm volatile("s_waitcnt vmcnt(4)" ::: "memory");
  __builtin_amdgcn_sched_barrier(0);
  __builtin_amdgcn_s_barrier();
  __builtin_amdgcn_sched_barrier(0);

  for (int j = 0; j < NIT; ++j) {
    int t1  = 2*j + 1;
    int tn0 = (2*j + 2) & (NKT - 1);   // wraps on final iters (garbage, unconsumed)
    int tn1 = (2*j + 3) & (NKT - 1);
    G_PHASE(0, 0, 0, true,  false, { stageA(1, 1, t1);  });
    G_PHASE(0, 0, 1, false, false, { stageB(1, 1, t1);  });
    G_PHASE(0, 1, 1, true,  false, { stageA(0, 0, tn0); });
    G_PHASE(0, 1, 0, false, true,  { stageB(0, 0, tn0); });
    G_PHASE(1, 0, 0, true,  false, { stageA(0, 1, tn0); });
    G_PHASE(1, 0, 1, false, false, { stageB(0, 1, tn0); });
    G_PHASE(1, 1, 1, true,  false, { stageA(1, 0, tn1); });
    G_PHASE(1, 1, 0, false, true,  { stageB(1, 0, tn1); });
  }
  asm volatile("s_waitcnt vmcnt(0)" ::: "memory");   // drain dangling stages

  int rbase = m0 + wr*128 + lg*4;
  int cbase = n0 + wc*64 + li;
#pragma unroll
  for (int am = 0; am < 8; ++am)
#pragma unroll
    for (int nf = 0; nf < 4; ++nf)
#pragma unroll
      for (int r = 0; r < 4; ++r) {
        size_t off = (size_t)(rbase + am*16 + r) * Nd + (cbase + nf*16);
        if constexpr (sizeof(OutT) == 2) C[off] = f2bf(acc[am][nf][r]);
        else                             C[off] = acc[am][nf][r];
      }
}

// ---------------- causal flash attention, 32x32 swapped-QK^T ----------------
__global__ __launch_bounds__(512, 2) void flash_attn_kernel(
    const u16* __restrict__ Q, const u16* __restrict__ K, const u16* __restrict__ V,
    u16* __restrict__ O) {
  __shared__ __align__(16) u16 Ks[2*64*128];  // 32 KB swizzled [kv][dh]
  __shared__ __align__(16) u16 Vt[2*128*64];  // 32 KB swizzled [dh][kv]
  int tid = threadIdx.x, wv = tid >> 6, lane = tid & 63;
  int ql = lane & 31, hi = lane >> 5;
  int b = blockIdx.x >> 4, h = blockIdx.x & 15;
  int qt = (int)gridDim.y - 1 - (int)blockIdx.y;
  int q0 = qt << 8;
  int qw = q0 + wv*32;          // wave q base
  int qa = qw + ql;             // this lane's q row
  int swzl = (ql & 7) << 4;     // LDS XOR swizzle for this lane's rows
  const float qscale = 0.08838834764831845f * 1.4426950408889634f; // /sqrt(128)*log2e

  // Q fragments: B-frag layout (col q = lane&31, k = hi*8+j), 8 d-slices of 16
  bf16x8 qf[8];
  {
    const u16* qp = Q + (size_t)(b*NS + qa) * ND + h*NDH + hi*8;
#pragma unroll
    for (int ds = 0; ds < 8; ++ds) {
      u16x8 t = *(const u16x8*)(qp + ds*16);
      u16x8 r;
#pragma unroll
      for (int j = 0; j < 8; ++j) r[j] = f2bf(bf2f(t[j]) * qscale);
      qf[ds] = *(bf16x8*)&r;
    }
  }
  f32x16 o0 = {}, o1 = {}, o2 = {}, o3 = {};   // O dh-subtiles 0..3
  float m_run = -INFINITY, l_run = 0.f;

  const char* Kg = (const char*)(K + (size_t)b*NS*ND + h*NDH);
  const char* Vg = (const char*)(V + (size_t)b*NS*ND + h*NDH);
  const int ROWB = ND * 2;

  int p   = tid & 31;    // dh pair for V repack
  int kvg = tid >> 5;    // kv chunk 0..15 (4 kv rows each)

  auto issueKV = [&](int kv0, int buf, unsigned (&dlo)[4], unsigned (&dhi)[4]) {
    const char* vrow = Vg + (size_t)(kv0 + kvg*4) * ROWB;
#pragma unroll
    for (int j = 0; j < 4; ++j) {
      dlo[j] = *(const unsigned*)(vrow + j*ROWB + p*4);
      dhi[j] = *(const unsigned*)(vrow + j*ROWB + 128 + p*4);
    }
    char* ksb = (char*)Ks + buf*16384;
#pragma unroll
    for (int c = 0; c < 2; ++c) {
      int s = c*8192 + wv*1024 + lane*16;
      int row = s >> 8;
      int within = (s & 255) ^ ((row & 7) << 4);
      gld16(Kg + (size_t)(kv0 + row)*ROWB + within, ksb + c*8192 + wv*1024);
    }
    __builtin_amdgcn_sched_barrier(0);
  };

  auto dostep = [&](int kv0, int buf, const unsigned (&dlo)[4], const unsigned (&dhi)[4],
                    bool hasNext) {
    if (hasNext) asm volatile("s_waitcnt vmcnt(10)" ::: "memory");
    else         asm volatile("s_waitcnt vmcnt(0)"  ::: "memory");
    __builtin_amdgcn_sched_barrier(0);
    __builtin_amdgcn_s_barrier();        // BAR-A: all waves' K(t) landed
    __builtin_amdgcn_sched_barrier(0);

    char* vtb = (char*)Vt + buf*16384;
    const char* ksb = (const char*)Ks + buf*16384;

    // Vt write: in-register repack (4 kv per thread), swizzled b64 stores
    {
      u16x4 rA, rB, rC, rD;
#pragma unroll
      for (int j = 0; j < 4; ++j) {
        rA[j] = (u16)dlo[j]; rB[j] = (u16)(dlo[j] >> 16);
        rC[j] = (u16)dhi[j]; rD[j] = (u16)(dhi[j] >> 16);
      }
      int a0 = ((2*p   )*128 + kvg*8) ^ (((2*p  ) & 7) << 4);
      int a1 = ((2*p+ 1)*128 + kvg*8) ^ (((2*p+1) & 7) << 4);
      int a2 = ((2*p+64)*128 + kvg*8) ^ (((2*p  ) & 7) << 4);
      int a3 = ((2*p+65)*128 + kvg*8) ^ (((2*p+1) & 7) << 4);
      *(u16x4*)(vtb + a0) = rA;
      *(u16x4*)(vtb + a1) = rB;
      *(u16x4*)(vtb + a2) = rC;
      *(u16x4*)(vtb + a3) = rD;
    }

    // S = K Q^T (swapped): p0 = kv 0..31, p1 = kv 32..63; lane's q = ql
    f32x16 p0 = {}, p1 = {};
    __builtin_amdgcn_s_setprio(1);
#pragma unroll
    for (int ds = 0; ds < 8; ++ds) {
      bf16x8 kf0 = *(const bf16x8*)(ksb + ((ql*256 + ds*32 + hi*16) ^ swzl));
      p0 = mfma32_bf16(kf0, qf[ds], p0);
      bf16x8 kf1 = *(const bf16x8*)(ksb + (((32+ql)*256 + ds*32 + hi*16) ^ swzl));
      p1 = mfma32_bf16(kf1, qf[ds], p1);
    }
    __builtin_amdgcn_s_setprio(0);

    // causal mask: kv_abs = kv0 + s*32 + (r&3)+8*(r>>2)+4*hi  vs  qa
    if (kv0 + 63 > qw) {
      int thresh = qa - kv0 - 4*hi;
#pragma unroll
      for (int r = 0; r < 16; ++r) {
        int c0 = (r & 3) + 8*(r >> 2);
        p0[r] = (c0      > thresh) ? -INFINITY : p0[r];
        p1[r] = (c0 + 32 > thresh) ? -INFINITY : p1[r];
      }
    }

    // row max (in-reg tree + one cross-pair shuffle)
    float mx[16];
#pragma unroll
    for (int r = 0; r < 16; ++r) mx[r] = fmaxf(p0[r], p1[r]);
#pragma unroll
    for (int s = 8; s > 0; s >>= 1)
#pragma unroll
      for (int r = 0; r < 8; ++r) if (r < s) mx[r] = fmaxf(mx[r], mx[r + s]);
    float pmax = fmaxf(mx[0], __shfl_xor(mx[0], 32, 64));

    // T13 defer-max
    if (!__all(pmax <= m_run + 8.f)) {
      float mn = fmaxf(m_run, pmax);
      float corr = __builtin_amdgcn_exp2f(m_run - mn);
      m_run = mn; l_run *= corr;
#pragma unroll
      for (int r = 0; r < 16; ++r) {
        float cw = __shfl(corr, (r & 3) + 8*(r >> 2) + 4*hi, 64);
        o0[r] *= cw; o1[r] *= cw; o2[r] *= cw; o3[r] *= cw;
      }
    }

    // exp2 + row sum
    float sm[16];
#pragma unroll
    for (int r = 0; r < 16; ++r) {
      p0[r] = __builtin_amdgcn_exp2f(p0[r] - m_run);
      p1[r] = __builtin_amdgcn_exp2f(p1[r] - m_run);
      sm[r] = p0[r] + p1[r];
    }
#pragma unroll
    for (int s = 8; s > 0; s >>= 1)
#pragma unroll
      for (int r = 0; r < 8; ++r) if (r < s) sm[r] += sm[r + s];
    l_run += sm[0] + __shfl_xor(sm[0], 32, 64);

    // P -> bf16 A-frags: 16 cvt_pk + 8 permlane32_swap (T12)
    bf16x8 pa0, pa1, pa2, pa3;
#define MKPA(P, B, OUT) {                              \
      unsigned a0 = cvtpk(P[(B)+0], P[(B)+1]);         \
      unsigned b0 = cvtpk(P[(B)+4], P[(B)+5]);         \
      p32swap(a0, b0);                                 \
      unsigned a1 = cvtpk(P[(B)+2], P[(B)+3]);         \
      unsigned b1 = cvtpk(P[(B)+6], P[(B)+7]);         \
      p32swap(a1, b1);                                 \
      u32x4_t w; w[0]=a0; w[1]=a1; w[2]=b0; w[3]=b1;   \
      OUT = *(bf16x8*)&w; }
    MKPA(p0, 0, pa0)
    MKPA(p0, 8, pa1)
    MKPA(p1, 0, pa2)
    MKPA(p1, 8, pa3)
#undef MKPA

    asm volatile("s_waitcnt lgkmcnt(0)" ::: "memory");  // my Vt writes done
    __builtin_amdgcn_sched_barrier(0);
    __builtin_amdgcn_s_barrier();        // BAR-B: all waves' Vt[buf] visible
    __builtin_amdgcn_sched_barrier(0);

    // O += P V  (A = P frag, B = V^T column frag)
    __builtin_amdgcn_s_setprio(1);
#define PVT(OT, T) {                                                        \
      _Pragma("unroll")                                                     \
      for (int ks = 0; ks < 4; ++ks) {                                      \
        int a = ((((T)*32 + ql)*128 + ks*32 + hi*16) ^ swzl);               \
        bf16x8 vf = *(const bf16x8*)(vtb + a);                              \
        OT = mfma32_bf16(ks==0?pa0:ks==1?pa1:ks==2?pa2:pa3, vf, OT);        \
      } }
    PVT(o0, 0)
    PVT(o1, 1)
    PVT(o2, 2)
    PVT(o3, 3)
#undef PVT
    __builtin_amdgcn_s_setprio(0);
  };

  int nt = 4*qt + 4;                     // kv tiles 0 .. q0+255
  unsigned dloA[4], dhiA[4], dloB[4], dhiB[4];
  issueKV(0, 0, dloA, dhiA);
  for (int t = 0; ; t += 2) {
    bool h1 = (t+1 < nt);
    if (h1) issueKV((t+1)*64, 1, dloB, dhiB);
    dostep(t*64, 0, dloA, dhiA, h1);
    if (!h1) break;
    bool h2 = (t+2 < nt);
    if (h2) issueKV((t+2)*64, 0, dloA, dhiA);
    dostep((t+1)*64, 1, dloB, dhiB, h2);
    if (!h2) break;
  }

  // epilogue: O rows q' = (r&3)+8*(r>>2)+4*hi, cols dh = t*32+ql
  float inv = 1.0f / l_run;
#pragma unroll
  for (int r = 0; r < 16; ++r) {
    int crow = (r & 3) + 8*(r >> 2) + 4*hi;
    float iv = __shfl(inv, crow, 64);
    size_t base = (size_t)(b*NS + qw + crow) * ND + h*NDH + ql;
    O[base +  0] = f2bf(o0[r] * iv);
    O[base + 32] = f2bf(o1[r] * iv);
    O[base + 64] = f2bf(o2[r] * iv);
    O[base + 96] = f2bf(o3[r] * iv);
  }
}

// ---------------- launch ----------------
extern "C" void kernel_launch(void* const* d_in, const int* in_sizes, int n_in,
                              void* d_out, int out_size, void* d_ws, size_t ws_size,
                              hipStream_t stream) {
  const float* x  = (const float*)d_in[0];
  // d_in[1] = attn_mask (causal, handled analytically)
  const float* Wq = (const float*)d_in[2];
  const float* Wk = (const float*)d_in[3];
  const float* Wv = (const float*)d_in[4];
  const float* Wo = (const float*)d_in[5];

  char* ws = (char*)d_ws;
  const size_t SZ_MD = (size_t)NM * ND * 2;
  const size_t SZ_W  = (size_t)ND * ND * 2;
  u16* xb  = (u16*)(ws);
  u16* Qb  = (u16*)(ws + SZ_MD);
  u16* Kb  = (u16*)(ws + 2*SZ_MD);
  u16* Vb  = (u16*)(ws + 3*SZ_MD);
  u16* Ab  = (u16*)(ws + 4*SZ_MD);
  u16* Wqb = (u16*)(ws + 5*SZ_MD);
  u16* Wkb = (u16*)(ws + 5*SZ_MD + SZ_W);
  u16* Wvb = (u16*)(ws + 5*SZ_MD + 2*SZ_W);
  u16* Wob = (u16*)(ws + 5*SZ_MD + 3*SZ_W);
  float* cosT = (float*)(ws + 5*SZ_MD + 4*SZ_W);
  float* sinT = (float*)(ws + 5*SZ_MD + 4*SZ_W + (size_t)NS*64*4);
  size_t needed = 5*SZ_MD + 4*SZ_W + 2*(size_t)NS*64*4;
  if (ws_size < needed) return;

  {
    int n8 = (NM * ND) / 8;
    cvt_bf16_kernel<<<(n8 + 255)/256, 256, 0, stream>>>(x, xb, n8);
    int w8 = (ND * ND) / 8;
    cvt_bf16_kernel<<<(w8 + 255)/256, 256, 0, stream>>>(Wq, Wqb, w8);
    cvt_bf16_kernel<<<(w8 + 255)/256, 256, 0, stream>>>(Wk, Wkb, w8);
    cvt_bf16_kernel<<<(w8 + 255)/256, 256, 0, stream>>>(Wv, Wvb, w8);
    cvt_bf16_kernel<<<(w8 + 255)/256, 256, 0, stream>>>(Wo, Wob, w8);
  }
  rope_tables_kernel<<<NS, 64, 0, stream>>>(cosT, sinT);

  const int GEMM_GRID = (NM/256) * (ND/256);   // 256, %8==0
  gemm256_kernel<u16><<<GEMM_GRID, 512, 0, stream>>>(xb, Wqb, Qb, ND, ND);
  gemm256_kernel<u16><<<GEMM_GRID, 512, 0, stream>>>(xb, Wkb, Kb, ND, ND);
  gemm256_kernel<u16><<<GEMM_GRID, 512, 0, stream>>>(xb, Wvb, Vb, ND, ND);

  {
    int nthr = NM * NH * 8;
    rope_apply_kernel<<<nthr/256, 256, 0, stream>>>(Qb, cosT, sinT);
    rope_apply_kernel<<<nthr/256, 256, 0, stream>>>(Kb, cosT, sinT);
  }

  flash_attn_kernel<<<dim3(NB*NH, NS/256), 512, 0, stream>>>(Qb, Kb, Vb, Ab);

  gemm256_kernel<float><<<GEMM_GRID, 512, 0, stream>>>(Ab, Wob, (float*)d_out, ND, ND);
}